// Round 11
// baseline (526.815 us; speedup 1.0000x reference)
//
#include <hip/hip_runtime.h>
#include <math.h>

// ---------------------------------------------------------------------------
// STPGCN forward. fp32 I/O, bf16 MFMA internal, fp32 accumulate.
// R11: mega-kernel (R9 phase bodies verbatim) with a HAND-ROLLED grid barrier
// (device-scope atomics + threadfence) instead of R10's cooperative launch,
// which silently failed on this harness. 256 blocks on 256 CUs, 36.9KB LDS,
// __launch_bounds__(256,1) -> 1 block/CU, co-residency structurally assured.
// Barrier counters live in d_ws, zeroed by a captured hipMemsetAsync node.
// ---------------------------------------------------------------------------

typedef unsigned short u16;
typedef __attribute__((ext_vector_type(8))) short short8;
typedef __attribute__((ext_vector_type(4))) float f32x4;
typedef __attribute__((ext_vector_type(8))) unsigned short u16x8;
typedef __attribute__((ext_vector_type(4))) unsigned short u16x4;

#define MFMA16(a, b, c) __builtin_amdgcn_mfma_f32_16x16x32_bf16((a), (b), (c), 0, 0, 0)

__device__ __forceinline__ float b2f(u16 u) {
  union { unsigned int i; float f; } x; x.i = ((unsigned int)u) << 16; return x.f;
}
__device__ __forceinline__ u16 f2b(float f) {
  union { float f; unsigned int i; } x; x.f = f;
  unsigned int r = x.i + 0x7FFFu + ((x.i >> 16) & 1u);
  return (u16)(r >> 16);
}
__device__ __forceinline__ void ld8f(const float* __restrict__ p, float* f) {
  f32x4 a = *(const f32x4*)p;
  f32x4 b = *(const f32x4*)(p + 4);
  #pragma unroll
  for (int i = 0; i < 4; ++i) { f[i] = a[i]; f[4 + i] = b[i]; }
}
__device__ __forceinline__ float gcf(const float* e, const float* __restrict__ mu,
                                     const float* __restrict__ sg) {
  float s = 0.f;
  #pragma unroll
  for (int i = 0; i < 8; ++i) {
    float dm = e[i] - mu[i];
    s += dm * dm * sg[i] * sg[i];
  }
  return -0.5f * s;
}
__device__ __forceinline__ float sigm(float v) { return 1.0f / (1.0f + expf(-v)); }

// grid barrier: arrive (device-scope atomic) + spin; threadfence = agent-scope
// release/acquire (writes back / invalidates L1+XCD L2 -> cross-XCD safe).
__device__ __forceinline__ void gsync(int* bar) {
  __syncthreads();
  if (threadIdx.x == 0) {
    __threadfence();
    atomicAdd(bar, 1);
    while (atomicAdd(bar, 0) < 256) __builtin_amdgcn_s_sleep(8);
    __threadfence();
  }
  __syncthreads();
}

struct MegaArgs {
  const float *x, *sape, *tape, *srpe, *trpe, *Wi, *bi, *gmu, *gsg, *Wg, *bg,
              *Wsp, *Wtp, *fsw, *mask, *g1w, *gw, *ow, *fsb, *g1b, *gob, *obv;
  u16 *hT_a, *hT_b, *Abf, *G, *fswT, *WgT, *g1wB, *gwB, *owB, *yB, *catB, *sB;
  float *spb, *tpb, *ev, *ypt;
  float *outp;
  int *bars;
};

// ---------------------------------------------------------------------------
// prep body (R9-identical). jobs: 4463
// ---------------------------------------------------------------------------
__device__ void prep_body(const MegaArgs& a, int bid) {
  const int tid = threadIdx.x;

  if (bid < 768) {  // h0 -> hT0[b][t][c][i]
    int gid = bid * 256 + tid;
    int i8 = gid & 63, c = (gid >> 6) & 63, bt = gid >> 12;
    float xv[8];
    ld8f(&a.x[bt * 512 + i8 * 8], xv);
    float wic = a.Wi[c], bic = a.bi[c];
    u16x8 hv;
    #pragma unroll
    for (int ii = 0; ii < 8; ++ii) hv[ii] = f2b(xv[ii] * wic + bic);
    *(u16x8*)&a.hT_a[gid * 8] = hv;
    return;
  }
  bid -= 768;
  if (bid < 1024) {  // Abf
    int gid = bid * 256 + tid;
    int i = gid & 511, j = gid >> 9;
    float fi[8], fj[8], fr[8];
    ld8f(a.sape + i * 8, fi);
    ld8f(a.sape + j * 8, fj);
    ld8f(a.srpe + ((size_t)i * 512 + j) * 8, fr);
    u16 eb[4];
    #pragma unroll
    for (int l = 0; l < 4; ++l) {
      const float* mub = a.gmu + l * 48;
      const float* sgb = a.gsg + l * 48;
      float s = gcf(fi, mub + 0, sgb + 0)
              + gcf(fj, mub + 8, sgb + 8)
              + gcf(fr, mub + 32, sgb + 32);
      eb[l] = f2b(expf(s));
    }
    #pragma unroll
    for (int b = 0; b < 4; ++b)
      #pragma unroll
      for (int k = 0; k < 3; ++k) {
        float mv = a.mask[((size_t)(b * 512 + j)) * 1536 + k * 512 + i];
        u16 m = (mv != 0.f) ? (u16)0xFFFFu : (u16)0;
        #pragma unroll
        for (int l = 0; l < 4; ++l)
          a.Abf[((size_t)((l * 4 + b) * 512 + j)) * 1536 + k * 512 + i] = eb[l] & m;
      }
    return;
  }
  bid -= 1024;
  if (bid < 1024) {  // spb
    int gid = bid * 256 + tid;
    int o = gid & 127, j = (gid >> 7) & 511, l = gid >> 16;
    float s = 0.f;
    #pragma unroll
    for (int dd = 0; dd < 8; ++dd)
      s += a.sape[j * 8 + dd] * a.Wsp[(l * 8 + dd) * 128 + o];
    a.spb[gid] = s;
    return;
  }
  bid -= 1024;
  if (bid < 96) {  // tpb
    int gid = bid * 256 + tid;
    int o = gid & 127, bt = (gid >> 7) % 48, l = gid / 6144;
    float s = a.bg[l * 128 + o];
    #pragma unroll
    for (int dd = 0; dd < 8; ++dd)
      s += a.tape[bt * 8 + dd] * a.Wtp[(l * 8 + dd) * 128 + o];
    a.tpb[gid] = s;
    return;
  }
  bid -= 96;
  if (bid < 768) {  // fswT
    int gid = bid * 256 + tid;
    int kidx = gid % 768, rest = gid / 768;
    int o = rest & 63, l = rest >> 6;
    int c = kidx & 63, tt = kidx >> 6;
    a.fswT[gid] = f2b(a.fsw[((l * 64 + o) * 64 + c) * 12 + tt]);
    return;
  }
  bid -= 768;
  if (bid < 128) {  // WgT
    int gid = bid * 256 + tid;
    int c = gid & 63, o = (gid >> 6) & 127, l = gid >> 13;
    a.WgT[gid] = f2b(a.Wg[(l * 64 + c) * 128 + o]);
    return;
  }
  bid -= 128;
  if (bid < 3) {  // ev
    int gid = bid * 256 + tid;
    if (gid < 576) {
      int k = gid % 3, t = (gid / 3) % 12, b = (gid / 36) % 4, l = gid / 144;
      const float* mub = a.gmu + l * 48;
      const float* sgb = a.gsg + l * 48;
      float e2[8], e3[8], e5[8];
      ld8f(a.tape + (b * 12 + t) * 8, e2);
      int tp = t + k - 2;
      if (tp >= 0) ld8f(a.tape + (b * 12 + tp) * 8, e3);
      else {
        #pragma unroll
        for (int ii = 0; ii < 8; ++ii) e3[ii] = 0.f;
      }
      ld8f(a.trpe + k * 8, e5);
      float s = gcf(e2, mub + 16, sgb + 16)
              + gcf(e3, mub + 24, sgb + 24)
              + gcf(e5, mub + 40, sgb + 40);
      a.ev[gid] = expf(s);
    }
    return;
  }
  bid -= 3;
  if (bid < 128) { int gid = bid * 256 + tid; a.g1wB[gid] = f2b(a.g1w[gid]); return; }
  bid -= 128;
  if (bid < 512) { int gid = bid * 256 + tid; a.gwB[gid] = f2b(a.gw[gid]); return; }
  bid -= 512;
  { int gid = bid * 256 + tid; if (gid < 3072) a.owB[gid] = f2b(a.ow[gid]); }
}

// ---------------------------------------------------------------------------
// agg body (R9-identical). jobs: 288. smem: As[128][72] | Bs[128][72]
// ---------------------------------------------------------------------------
__device__ void agg_body(const MegaArgs& a, int bid, const u16* __restrict__ Abfl,
                         const u16* __restrict__ hT, char* smem) {
  u16 (*As)[72] = (u16 (*)[72])smem;
  u16 (*Bs)[72] = (u16 (*)[72])(smem + 18432);
  const int tid = threadIdx.x, wid = tid >> 6, lane = tid & 63;
  const int l16 = lane & 15, quad = lane >> 4;
  const int nt = bid % 6;
  const int mt = (bid / 6) & 3;
  const int k  = (bid / 24) % 3;
  const int b  = bid / 72;
  const int wm = wid >> 1, wn = wid & 1;

  const u16* Arow0 = Abfl + ((size_t)(b * 512 + mt * 128)) * 1536 + k * 512;
  f32x4 acc[4][4] = {};

  for (int it = 0; it < 8; ++it) {
    const int i0 = it * 64;
    #pragma unroll
    for (int s = 0; s < 4; ++s) {
      int idx = s * 256 + tid;
      int r = idx >> 3, ch = (idx & 7) * 8;
      *(u16x8*)&As[r][ch] = *(const u16x8*)&Arow0[(size_t)r * 1536 + i0 + ch];
      int tp = nt * 2 + (r >> 6), c = r & 63;
      *(u16x8*)&Bs[r][ch] =
          *(const u16x8*)&hT[((size_t)((b * 12 + tp) * 64 + c)) * 512 + i0 + ch];
    }
    __syncthreads();
    #pragma unroll
    for (int ks = 0; ks < 2; ++ks) {
      short8 af[4], bf[4];
      #pragma unroll
      for (int mb = 0; mb < 4; ++mb)
        af[mb] = *(const short8*)&As[wm * 64 + mb * 16 + l16][ks * 32 + quad * 8];
      #pragma unroll
      for (int nb = 0; nb < 4; ++nb)
        bf[nb] = *(const short8*)&Bs[wn * 64 + nb * 16 + l16][ks * 32 + quad * 8];
      #pragma unroll
      for (int mb = 0; mb < 4; ++mb)
        #pragma unroll
        for (int nb = 0; nb < 4; ++nb)
          acc[mb][nb] = MFMA16(af[mb], bf[nb], acc[mb][nb]);
    }
    __syncthreads();
  }

  u16* base = (u16*)smem;  // stage C 128x128 bf16 = 32KB
  #pragma unroll
  for (int mb = 0; mb < 4; ++mb)
    #pragma unroll
    for (int nb = 0; nb < 4; ++nb) {
      int n = wn * 64 + nb * 16 + l16;
      #pragma unroll
      for (int r = 0; r < 4; ++r) {
        int m = wm * 64 + mb * 16 + quad * 4 + r;
        base[m * 128 + n] = f2b(acc[mb][nb][r]);
      }
    }
  __syncthreads();
  u16* Gp = a.G + ((size_t)((b * 3 + k) * 512 + mt * 128)) * 768 + nt * 128;
  #pragma unroll
  for (int s = 0; s < 8; ++s) {
    int idx = s * 256 + tid;
    int m = idx >> 4, ch = (idx & 15) * 8;
    *(u16x8*)&Gp[(size_t)m * 768 + ch] = *(const u16x8*)&base[m * 128 + ch];
  }
  __syncthreads();  // protect smem reuse by next job
}

// ---------------------------------------------------------------------------
// combine body (R9-identical). jobs: 192. smem: aggL[128][72] | hL[128][72]
// ---------------------------------------------------------------------------
__device__ void combine_body(const MegaArgs& a, int bid, int l,
                             u16* __restrict__ hTout, char* smem) {
  u16 (*aggL)[72] = (u16 (*)[72])smem;
  u16 (*hL)[72]   = (u16 (*)[72])(smem + 18432);
  const float* evl  = a.ev  + l * 144;
  const u16*   WgTl = a.WgT + l * 8192;
  const float* spbl = a.spb + l * 65536;
  const float* tpbl = a.tpb + l * 6144;
  const u16*   fswTl = a.fswT + l * 49152;
  float* yptl = a.ypt + (size_t)l * 1572864;

  const int tid = threadIdx.x, wid = tid >> 6, lane = tid & 63;
  const int l16 = lane & 15, quad = lane >> 4;
  const int mt = bid & 3;
  const int bt = bid >> 2;
  const int b = bt / 12, t = bt - b * 12;

  {  // combine G over k (fp32)
    int j = tid >> 1;
    int c0 = (tid & 1) * 32;
    float accv[32];
    #pragma unroll
    for (int ii = 0; ii < 32; ++ii) accv[ii] = 0.f;
    #pragma unroll
    for (int k = 0; k < 3; ++k) {
      int tp = t + k - 2;
      if (tp < 0) continue;
      float ek = evl[bt * 3 + k];
      const u16* gp = &a.G[((size_t)((b * 3 + k) * 512 + mt * 128 + j)) * 768 + tp * 64 + c0];
      #pragma unroll
      for (int s = 0; s < 4; ++s) {
        u16x8 gv = *(const u16x8*)&gp[s * 8];
        #pragma unroll
        for (int ii = 0; ii < 8; ++ii) accv[s * 8 + ii] += b2f(gv[ii]) * ek;
      }
    }
    #pragma unroll
    for (int s = 0; s < 4; ++s) {
      u16x8 ov;
      #pragma unroll
      for (int ii = 0; ii < 8; ++ii) ov[ii] = f2b(accv[s * 8 + ii]);
      *(u16x8*)&aggL[j][c0 + s * 8] = ov;
    }
  }
  __syncthreads();

  f32x4 acc2[8][2] = {};
  #pragma unroll
  for (int ks = 0; ks < 2; ++ks) {
    short8 bf[2];
    #pragma unroll
    for (int nb = 0; nb < 2; ++nb)
      bf[nb] = *(const short8*)&aggL[wid * 32 + nb * 16 + l16][ks * 32 + quad * 8];
    #pragma unroll
    for (int mb = 0; mb < 8; ++mb) {
      short8 aa = *(const short8*)&WgTl[(mb * 16 + l16) * 64 + ks * 32 + quad * 8];
      acc2[mb][0] = MFMA16(aa, bf[0], acc2[mb][0]);
      acc2[mb][1] = MFMA16(aa, bf[1], acc2[mb][1]);
    }
  }

  #pragma unroll
  for (int mb = 0; mb < 4; ++mb) {
    int ob = mb * 16 + quad * 4;
    #pragma unroll
    for (int nb = 0; nb < 2; ++nb) {
      int jl = wid * 32 + nb * 16 + l16;
      int jg = mt * 128 + jl;
      f32x4 spl = *(const f32x4*)&spbl[jg * 128 + ob];
      f32x4 spr = *(const f32x4*)&spbl[jg * 128 + 64 + ob];
      f32x4 tpl = *(const f32x4*)&tpbl[bt * 128 + ob];
      f32x4 tpr = *(const f32x4*)&tpbl[bt * 128 + 64 + ob];
      #pragma unroll
      for (int r = 0; r < 4; ++r) {
        float vl = acc2[mb][nb][r] + spl[r] + tpl[r];
        float vr = acc2[mb + 4][nb][r] + spr[r] + tpr[r];
        u16 hb = f2b(vl * sigm(vr));
        hTout[((size_t)((b * 12 + t) * 64 + ob + r)) * 512 + jg] = hb;
        hL[jl][ob + r] = hb;
      }
    }
  }
  __syncthreads();

  f32x4 accY[4][2] = {};
  #pragma unroll
  for (int ks = 0; ks < 2; ++ks) {
    short8 bfv[2];
    #pragma unroll
    for (int nb = 0; nb < 2; ++nb)
      bfv[nb] = *(const short8*)&hL[wid * 32 + nb * 16 + l16][ks * 32 + quad * 8];
    #pragma unroll
    for (int mb = 0; mb < 4; ++mb) {
      short8 aa = *(const short8*)&fswTl[(mb * 16 + l16) * 768 + t * 64 + ks * 32 + quad * 8];
      accY[mb][0] = MFMA16(aa, bfv[0], accY[mb][0]);
      accY[mb][1] = MFMA16(aa, bfv[1], accY[mb][1]);
    }
  }
  #pragma unroll
  for (int mb = 0; mb < 4; ++mb)
    #pragma unroll
    for (int nb = 0; nb < 2; ++nb) {
      int j = mt * 128 + wid * 32 + nb * 16 + l16;
      #pragma unroll
      for (int r = 0; r < 4; ++r) {
        int o = mb * 16 + quad * 4 + r;
        yptl[((size_t)(bt * 64 + o)) * 512 + j] = accY[mb][nb][r];
      }
    }
  __syncthreads();
}

// ---------------------------------------------------------------------------
// reduce body (R9-identical). jobs: 512
// ---------------------------------------------------------------------------
__device__ void reduce_body(const MegaArgs& a, int bid) {
  int gid = bid * 256 + threadIdx.x;
  int j4 = gid & 127, o = (gid >> 7) & 63, b = (gid >> 13) & 3, l = gid >> 15;
  const float* base = &a.ypt[(size_t)l * 1572864 +
                             ((size_t)((b * 12) * 64 + o)) * 512 + j4 * 4];
  float fb = a.fsb[l * 64 + o];
  f32x4 s = {fb, fb, fb, fb};
  #pragma unroll
  for (int t = 0; t < 12; ++t) s += *(const f32x4*)&base[(size_t)t * 32768];
  u16x4 pk;
  #pragma unroll
  for (int ii = 0; ii < 4; ++ii) pk[ii] = f2b(s[ii]);
  *(u16x4*)&a.yB[((size_t)((l * 4 + b) * 64 + o)) * 512 + j4 * 4] = pk;
}

// ---------------------------------------------------------------------------
// glu1cat body (R9-identical). jobs: 64. smem: yL[128][72]
// ---------------------------------------------------------------------------
__device__ void glu1cat_body(const MegaArgs& a, int bid, char* smem) {
  u16 (*yL)[72] = (u16 (*)[72])smem;
  const int tid = threadIdx.x, wid = tid >> 6, lane = tid & 63;
  const int l16 = lane & 15, quad = lane >> 4;
  const int l = bid >> 4;
  const int b = (bid >> 2) & 3;
  const int v0 = (bid & 3) * 128;

  {
    int o = tid & 63, sv = tid >> 6;
    const u16* src = &a.yB[((size_t)((l * 4 + b) * 64 + o)) * 512 + v0 + sv * 32];
    u16x8 p0 = *(const u16x8*)&src[0];
    u16x8 p1 = *(const u16x8*)&src[8];
    u16x8 p2 = *(const u16x8*)&src[16];
    u16x8 p3 = *(const u16x8*)&src[24];
    #pragma unroll
    for (int ii = 0; ii < 8; ++ii) {
      yL[sv * 32 + ii][o] = p0[ii];
      yL[sv * 32 + 8 + ii][o] = p1[ii];
      yL[sv * 32 + 16 + ii][o] = p2[ii];
      yL[sv * 32 + 24 + ii][o] = p3[ii];
    }
  }
  __syncthreads();

  f32x4 acc[2][8] = {};
  #pragma unroll
  for (int ks = 0; ks < 2; ++ks) {
    short8 a0 = *(const short8*)&a.g1wB[l * 8192 + (wid * 16 + l16) * 64 +
                                        ks * 32 + quad * 8];
    short8 a1 = *(const short8*)&a.g1wB[l * 8192 + (64 + wid * 16 + l16) * 64 +
                                        ks * 32 + quad * 8];
    #pragma unroll
    for (int nb = 0; nb < 8; ++nb) {
      short8 bf = *(const short8*)&yL[nb * 16 + l16][ks * 32 + quad * 8];
      acc[0][nb] = MFMA16(a0, bf, acc[0][nb]);
      acc[1][nb] = MFMA16(a1, bf, acc[1][nb]);
    }
  }
  #pragma unroll
  for (int nb = 0; nb < 8; ++nb) {
    int v = v0 + nb * 16 + l16;
    int oc = wid * 16 + quad * 4;
    u16x4 pk;
    #pragma unroll
    for (int r = 0; r < 4; ++r) {
      float zl = acc[0][nb][r] + a.g1b[l * 128 + oc + r];
      float zr = acc[1][nb][r] + a.g1b[l * 128 + 64 + oc + r];
      pk[r] = f2b(zl * sigm(zr));
    }
    *(u16x4*)&a.catB[((size_t)(b * 512 + v)) * 256 + l * 64 + oc] = pk;
  }
  __syncthreads();
}

// ---------------------------------------------------------------------------
// gout body (R9-identical). jobs: 256. smem: cL[64][264]
// ---------------------------------------------------------------------------
__device__ void gout_body(const MegaArgs& a, int bid, char* smem) {
  u16 (*cL)[264] = (u16 (*)[264])smem;
  const int tid = threadIdx.x, wid = tid >> 6, lane = tid & 63;
  const int l16 = lane & 15, quad = lane >> 4;
  const int wm = wid >> 1, wn = wid & 1;
  const int b = bid >> 6;
  const int v0 = ((bid >> 3) & 7) * 64;
  const int cc0 = (bid & 7) * 32;

  {
    int v = tid >> 2, seg = (tid & 3) * 64;
    const u16* src = &a.catB[((size_t)(b * 512 + v0 + v)) * 256 + seg];
    #pragma unroll
    for (int s = 0; s < 8; ++s)
      *(u16x8*)&cL[v][seg + s * 8] = *(const u16x8*)&src[s * 8];
  }
  __syncthreads();

  f32x4 acc[2][2] = {};
  #pragma unroll
  for (int ks = 0; ks < 8; ++ks) {
    short8 aL = *(const short8*)&a.gwB[(cc0 + wm * 16 + l16) * 256 +
                                       ks * 32 + quad * 8];
    short8 aH = *(const short8*)&a.gwB[(256 + cc0 + wm * 16 + l16) * 256 +
                                       ks * 32 + quad * 8];
    #pragma unroll
    for (int nb = 0; nb < 2; ++nb) {
      short8 bf = *(const short8*)&cL[wn * 32 + nb * 16 + l16][ks * 32 + quad * 8];
      acc[0][nb] = MFMA16(aL, bf, acc[0][nb]);
      acc[1][nb] = MFMA16(aH, bf, acc[1][nb]);
    }
  }
  #pragma unroll
  for (int nb = 0; nb < 2; ++nb) {
    int v = v0 + wn * 32 + nb * 16 + l16;
    int cc = cc0 + wm * 16 + quad * 4;
    u16x4 pk;
    #pragma unroll
    for (int r = 0; r < 4; ++r) {
      float zl = acc[0][nb][r] + a.gob[cc + r];
      float zr = acc[1][nb][r] + a.gob[256 + cc + r];
      pk[r] = f2b(zl * sigm(zr));
    }
    *(u16x4*)&a.sB[((size_t)(b * 512 + v)) * 256 + cc] = pk;
  }
  __syncthreads();
}

// ---------------------------------------------------------------------------
// head body (R9-identical). jobs: 32
// ---------------------------------------------------------------------------
__device__ void head_body(const MegaArgs& a, int bid) {
  const int tid = threadIdx.x, wid = tid >> 6, lane = tid & 63;
  const int l16 = lane & 15, quad = lane >> 4;
  const int b = bid >> 3;
  const int v0 = (bid & 7) * 64;

  f32x4 acc = {};
  #pragma unroll
  for (int ks = 0; ks < 8; ++ks) {
    short8 aa;
    if (l16 < 12) aa = *(const short8*)&a.owB[l16 * 256 + ks * 32 + quad * 8];
    else {
      #pragma unroll
      for (int ii = 0; ii < 8; ++ii) aa[ii] = 0;
    }
    short8 bf = *(const short8*)&a.sB[((size_t)(b * 512 + v0 + wid * 16 + l16)) * 256 +
                                      ks * 32 + quad * 8];
    acc = MFMA16(aa, bf, acc);
  }
  #pragma unroll
  for (int r = 0; r < 4; ++r) {
    int p = quad * 4 + r;
    if (p < 12)
      a.outp[(b * 12 + p) * 512 + v0 + wid * 16 + l16] = acc[r] + a.obv[p];
  }
}

// ---------------------------------------------------------------------------
// mega kernel: 13 phases, 12 manual grid barriers. grid 256 x 256, 1 block/CU.
// ---------------------------------------------------------------------------
__global__ __launch_bounds__(256, 1) void mega_kernel(MegaArgs a) {
  __shared__ __align__(16) char smem[36864];

  for (int job = blockIdx.x; job < 4463; job += 256) prep_body(a, job);
  gsync(&a.bars[0]);

  for (int l = 0; l < 4; ++l) {
    const u16* hin = (l & 1) ? a.hT_b : a.hT_a;
    u16* hout = (l & 1) ? a.hT_a : a.hT_b;
    const u16* Abfl = a.Abf + (size_t)l * 3145728;
    for (int job = blockIdx.x; job < 288; job += 256)
      agg_body(a, job, Abfl, hin, smem);
    gsync(&a.bars[1 + 2 * l]);
    for (int job = blockIdx.x; job < 192; job += 256)
      combine_body(a, job, l, hout, smem);
    gsync(&a.bars[2 + 2 * l]);
  }

  for (int job = blockIdx.x; job < 512; job += 256) reduce_body(a, job);
  gsync(&a.bars[9]);
  for (int job = blockIdx.x; job < 64; job += 256) glu1cat_body(a, job, smem);
  gsync(&a.bars[10]);
  for (int job = blockIdx.x; job < 256; job += 256) gout_body(a, job, smem);
  gsync(&a.bars[11]);
  for (int job = blockIdx.x; job < 32; job += 256) head_body(a, job);
}

// ---------------------------------------------------------------------------
extern "C" void kernel_launch(void* const* d_in, const int* in_sizes, int n_in,
                              void* d_out, int out_size, void* d_ws, size_t ws_size,
                              hipStream_t stream) {
  char* w = (char*)d_ws;
  MegaArgs a;
  a.x    = (const float*)d_in[0];
  a.sape = (const float*)d_in[1];
  a.tape = (const float*)d_in[2];
  a.srpe = (const float*)d_in[3];
  a.trpe = (const float*)d_in[4];
  a.mask = (const float*)d_in[7];
  a.Wi   = (const float*)d_in[8];
  a.bi   = (const float*)d_in[9];
  a.gmu  = (const float*)d_in[10];
  a.gsg  = (const float*)d_in[11];
  a.Wg   = (const float*)d_in[12];
  a.bg   = (const float*)d_in[13];
  a.Wsp  = (const float*)d_in[14];
  a.Wtp  = (const float*)d_in[15];
  a.fsw  = (const float*)d_in[16];
  a.fsb  = (const float*)d_in[17];
  a.g1w  = (const float*)d_in[18];
  a.g1b  = (const float*)d_in[19];
  a.gw   = (const float*)d_in[20];
  a.gob  = (const float*)d_in[21];
  a.ow   = (const float*)d_in[22];
  a.obv  = (const float*)d_in[23];

  a.hT_a = (u16*)(w + 0);            // 3,145,728 B
  a.hT_b = (u16*)(w + 3145728);      // 3,145,728 B
  a.Abf  = (u16*)(w + 6291456);      // 25,165,824 B
  a.G    = (u16*)(w + 31457280);     // 9,437,184 B
  a.fswT = (u16*)(w + 40894464);     // 393,216 B
  a.WgT  = (u16*)(w + 41287680);     // 65,536 B
  a.g1wB = (u16*)(w + 41353216);     // 65,536 B
  a.gwB  = (u16*)(w + 41418752);     // 262,144 B
  a.owB  = (u16*)(w + 41680896);     // 6,144 B (pad 8192)
  a.spb  = (float*)(w + 41689088);   // 1,048,576 B
  a.tpb  = (float*)(w + 42737664);   // 98,304 B
  a.ev   = (float*)(w + 42835968);   // 9,216 B (pad 16384)
  a.ypt  = (float*)(w + 42852352);   // 25,165,824 B
  a.yB   = (u16*)(w + 68018176);     // 2,097,152 B
  a.catB = (u16*)(w + 70115328);     // 1,048,576 B
  a.sB   = (u16*)(w + 71163904);     // 1,048,576 B
  a.bars = (int*)(w + 72212480);     // 128 B (12 counters used)
  a.outp = (float*)d_out;

  hipMemsetAsync(a.bars, 0, 128, stream);     // zero barrier counters (graph node)
  mega_kernel<<<256, 256, 0, stream>>>(a);
}

// Round 12
// 263.193 us; speedup vs baseline: 2.0016x; 2.0016x over previous
//
#include <hip/hip_runtime.h>
#include <math.h>

// ---------------------------------------------------------------------------
// STPGCN forward. fp32 I/O, bf16 MFMA internal, fp32 accumulate.
// B=4 T=12 V=512 C=64 d=8 TS=3 P=12 L=4, BETA=2.
// R12 = R9 structure (best measured 247us; R11 mega-kernel refuted the
// launch-overhead theory: phases at 4 waves/CU took 446us) + two changes:
//  (1) Abf (25MB write + 100MB read) replaced by expbT (2MB bf16) + a
//      ballot-packed 393KB mask bitfield; agg stages A = select(bit, expb, 0)
//      from L2-hot data instead of cold-HBM Abf.
//  (2) agg K-split: 2 halves of K=256 -> grid 576 (2 co-resident blocks/CU,
//      4 serial rounds instead of 8); G stored as 2 partial halves, combine
//      sums them in fp32.
// ---------------------------------------------------------------------------

typedef unsigned short u16;
typedef unsigned char u8;
typedef unsigned long long u64;
typedef __attribute__((ext_vector_type(8))) short short8;
typedef __attribute__((ext_vector_type(4))) float f32x4;
typedef __attribute__((ext_vector_type(8))) unsigned short u16x8;
typedef __attribute__((ext_vector_type(4))) unsigned short u16x4;

#define MFMA16(a, b, c) __builtin_amdgcn_mfma_f32_16x16x32_bf16((a), (b), (c), 0, 0, 0)
#define GHALF 9437184  // elements per G half (u16)

__device__ __forceinline__ float b2f(u16 u) {
  union { unsigned int i; float f; } x; x.i = ((unsigned int)u) << 16; return x.f;
}
__device__ __forceinline__ u16 f2b(float f) {
  union { float f; unsigned int i; } x; x.f = f;
  unsigned int r = x.i + 0x7FFFu + ((x.i >> 16) & 1u);
  return (u16)(r >> 16);
}
__device__ __forceinline__ void ld8f(const float* __restrict__ p, float* f) {
  f32x4 a = *(const f32x4*)p;
  f32x4 b = *(const f32x4*)(p + 4);
  #pragma unroll
  for (int i = 0; i < 4; ++i) { f[i] = a[i]; f[4 + i] = b[i]; }
}
__device__ __forceinline__ float gcf(const float* e, const float* __restrict__ mu,
                                     const float* __restrict__ sg) {
  float s = 0.f;
  #pragma unroll
  for (int i = 0; i < 8; ++i) {
    float dm = e[i] - mu[i];
    s += dm * dm * sg[i] * sg[i];
  }
  return -0.5f * s;
}
__device__ __forceinline__ float sigm(float v) { return 1.0f / (1.0f + expf(-v)); }

// ---------------------------------------------------------------------------
// prep: h0, expbT[l][j][i] bf16 + mbits (ballot-packed mask), spb, tpb,
// fswT, WgT, ev, g1wB/gwB/owB. blocks: 768|1024|1024|96|768|128|3|128|512|12
// ---------------------------------------------------------------------------
__global__ __launch_bounds__(256) void prep_kernel(
    const float* __restrict__ x, const float* __restrict__ sape,
    const float* __restrict__ tape, const float* __restrict__ srpe,
    const float* __restrict__ trpe, const float* __restrict__ Wi,
    const float* __restrict__ bi, const float* __restrict__ gmu,
    const float* __restrict__ gsg, const float* __restrict__ Wg,
    const float* __restrict__ bg, const float* __restrict__ Wsp,
    const float* __restrict__ Wtp, const float* __restrict__ fsw,
    const float* __restrict__ mask,
    const float* __restrict__ g1w, const float* __restrict__ gw,
    const float* __restrict__ ow,
    u16* __restrict__ hT0, u16* __restrict__ expbT, u64* __restrict__ mbits,
    float* __restrict__ spb, float* __restrict__ tpb,
    u16* __restrict__ fswT, u16* __restrict__ WgT, float* __restrict__ ev,
    u16* __restrict__ g1wB, u16* __restrict__ gwB, u16* __restrict__ owB) {
  const int tid = threadIdx.x;
  int bid = blockIdx.x;

  if (bid < 768) {  // h0 -> hT0[b][t][c][i]
    int gid = bid * 256 + tid;                 // 196608 items
    int i8 = gid & 63, c = (gid >> 6) & 63, bt = gid >> 12;
    float xv[8];
    ld8f(&x[bt * 512 + i8 * 8], xv);
    float wic = Wi[c], bic = bi[c];
    u16x8 hv;
    #pragma unroll
    for (int ii = 0; ii < 8; ++ii) hv[ii] = f2b(xv[ii] * wic + bic);
    *(u16x8*)&hT0[gid * 8] = hv;
    return;
  }
  bid -= 768;
  if (bid < 1024) {  // expbT + mask bitpack; thread per (j,i)
    int gid = bid * 256 + tid;                 // 262144
    int i = gid & 511, j = gid >> 9;           // wave covers 64 consecutive i
    float fi[8], fj[8], fr[8];
    ld8f(sape + i * 8, fi);
    ld8f(sape + j * 8, fj);
    ld8f(srpe + ((size_t)i * 512 + j) * 8, fr);
    #pragma unroll
    for (int l = 0; l < 4; ++l) {
      const float* mub = gmu + l * 48;
      const float* sgb = gsg + l * 48;
      float s = gcf(fi, mub + 0, sgb + 0)
              + gcf(fj, mub + 8, sgb + 8)
              + gcf(fr, mub + 32, sgb + 32);
      expbT[l * 262144 + j * 512 + i] = f2b(expf(s));
    }
    #pragma unroll
    for (int b = 0; b < 4; ++b)
      #pragma unroll
      for (int k = 0; k < 3; ++k) {
        float mv = mask[((size_t)(b * 512 + j)) * 1536 + k * 512 + i];
        u64 bal = __ballot(mv != 0.f);         // bit n <-> lane n <-> i0+n
        if ((tid & 63) == 0)
          mbits[((size_t)((b * 512 + j) * 3 + k)) * 8 + (i >> 6)] = bal;
      }
    return;
  }
  bid -= 1024;
  if (bid < 1024) {  // spb[l][j][o] = sape[j]·Wsp[l][:,o]
    int gid = bid * 256 + tid;                 // 262144
    int o = gid & 127, j = (gid >> 7) & 511, l = gid >> 16;
    float s = 0.f;
    #pragma unroll
    for (int dd = 0; dd < 8; ++dd)
      s += sape[j * 8 + dd] * Wsp[(l * 8 + dd) * 128 + o];
    spb[gid] = s;
    return;
  }
  bid -= 1024;
  if (bid < 96) {  // tpb[l][bt][o] = bg[l][o] + tape[bt]·Wtp[l][:,o]
    int gid = bid * 256 + tid;                 // 24576
    int o = gid & 127, bt = (gid >> 7) % 48, l = gid / 6144;
    float s = bg[l * 128 + o];
    #pragma unroll
    for (int dd = 0; dd < 8; ++dd)
      s += tape[bt * 8 + dd] * Wtp[(l * 8 + dd) * 128 + o];
    tpb[gid] = s;
    return;
  }
  bid -= 96;
  if (bid < 768) {  // fswT[l][o][t*64+c] = fs_w[l][o][c][t]
    int gid = bid * 256 + tid;                 // 196608
    int kidx = gid % 768, rest = gid / 768;
    int o = rest & 63, l = rest >> 6;
    int c = kidx & 63, tt = kidx >> 6;
    fswT[gid] = f2b(fsw[((l * 64 + o) * 64 + c) * 12 + tt]);
    return;
  }
  bid -= 768;
  if (bid < 128) {  // WgT[l][o][c] = Wg[l][c][o]
    int gid = bid * 256 + tid;                 // 32768
    int c = gid & 63, o = (gid >> 6) & 127, l = gid >> 13;
    WgT[gid] = f2b(Wg[(l * 64 + c) * 128 + o]);
    return;
  }
  bid -= 128;
  if (bid < 3) {  // ev[l][bt][k]
    int gid = bid * 256 + tid;
    if (gid < 576) {
      int k = gid % 3, t = (gid / 3) % 12, b = (gid / 36) % 4, l = gid / 144;
      const float* mub = gmu + l * 48;
      const float* sgb = gsg + l * 48;
      float e2[8], e3[8], e5[8];
      ld8f(tape + (b * 12 + t) * 8, e2);
      int tp = t + k - 2;
      if (tp >= 0) ld8f(tape + (b * 12 + tp) * 8, e3);
      else {
        #pragma unroll
        for (int ii = 0; ii < 8; ++ii) e3[ii] = 0.f;
      }
      ld8f(trpe + k * 8, e5);
      float s = gcf(e2, mub + 16, sgb + 16)
              + gcf(e3, mub + 24, sgb + 24)
              + gcf(e5, mub + 40, sgb + 40);
      ev[gid] = expf(s);
    }
    return;
  }
  bid -= 3;
  if (bid < 128) {  // g1wB
    int gid = bid * 256 + tid;
    g1wB[gid] = f2b(g1w[gid]);
    return;
  }
  bid -= 128;
  if (bid < 512) {  // gwB
    int gid = bid * 256 + tid;
    gwB[gid] = f2b(gw[gid]);
    return;
  }
  bid -= 512;
  {  // owB
    int gid = bid * 256 + tid;
    if (gid < 3072) owB[gid] = f2b(ow[gid]);
  }
}

// ---------------------------------------------------------------------------
// agg: G[half][b,k,j,t'*64+c] = sum_{i in half} expb*maskbit * hT[b,t',c,i]
// grid 576 = b(4) x half(2) x k(3) x mt(4) x nt(6). 128x128 tile, K=256.
// A staged from expbT (L2-hot 512KB) + mbits byte select.
// ---------------------------------------------------------------------------
__global__ __launch_bounds__(256) void agg_kernel(
    const u16* __restrict__ ebl, const u8* __restrict__ mbytes,
    const u16* __restrict__ hT, u16* __restrict__ G) {
  __shared__ u16 As[128][72];
  __shared__ u16 Bs[128][72];
  const int tid = threadIdx.x, wid = tid >> 6, lane = tid & 63;
  const int l16 = lane & 15, quad = lane >> 4;
  const int bid = blockIdx.x;
  const int nt = bid % 6;
  const int mt = (bid / 6) & 3;
  const int k  = (bid / 24) % 3;
  const int half = (bid / 72) & 1;
  const int b  = bid / 144;
  const int wm = wid >> 1, wn = wid & 1;

  f32x4 acc[4][4] = {};

  for (int it = 0; it < 4; ++it) {
    const int i0 = half * 256 + it * 64;
    #pragma unroll
    for (int s = 0; s < 4; ++s) {
      int idx = s * 256 + tid;
      int r = idx >> 3, ch = (idx & 7) * 8;
      // A row: expbase * maskbit
      u16x8 ev = *(const u16x8*)&ebl[(size_t)(mt * 128 + r) * 512 + i0 + ch];
      u8 mby = mbytes[((size_t)((b * 512 + mt * 128 + r) * 3 + k)) * 64 +
                      ((i0 + ch) >> 3)];
      u16x8 av;
      #pragma unroll
      for (int ii = 0; ii < 8; ++ii) av[ii] = ((mby >> ii) & 1) ? ev[ii] : (u16)0;
      *(u16x8*)&As[r][ch] = av;
      int tp = nt * 2 + (r >> 6), c = r & 63;
      *(u16x8*)&Bs[r][ch] =
          *(const u16x8*)&hT[((size_t)((b * 12 + tp) * 64 + c)) * 512 + i0 + ch];
    }
    __syncthreads();
    #pragma unroll
    for (int ks = 0; ks < 2; ++ks) {
      short8 af[4], bf[4];
      #pragma unroll
      for (int mb = 0; mb < 4; ++mb)
        af[mb] = *(const short8*)&As[wm * 64 + mb * 16 + l16][ks * 32 + quad * 8];
      #pragma unroll
      for (int nb = 0; nb < 4; ++nb)
        bf[nb] = *(const short8*)&Bs[wn * 64 + nb * 16 + l16][ks * 32 + quad * 8];
      #pragma unroll
      for (int mb = 0; mb < 4; ++mb)
        #pragma unroll
        for (int nb = 0; nb < 4; ++nb)
          acc[mb][nb] = MFMA16(af[mb], bf[nb], acc[mb][nb]);
    }
    __syncthreads();
  }

  // stage C (128x128 bf16) in LDS over As/Bs, then coalesced write
  u16* base = &As[0][0];
  #pragma unroll
  for (int mb = 0; mb < 4; ++mb)
    #pragma unroll
    for (int nb = 0; nb < 4; ++nb) {
      int n = wn * 64 + nb * 16 + l16;
      #pragma unroll
      for (int r = 0; r < 4; ++r) {
        int m = wm * 64 + mb * 16 + quad * 4 + r;
        base[m * 128 + n] = f2b(acc[mb][nb][r]);
      }
    }
  __syncthreads();
  u16* Gp = G + (size_t)half * GHALF +
            ((size_t)((b * 3 + k) * 512 + mt * 128)) * 768 + nt * 128;
  #pragma unroll
  for (int s = 0; s < 8; ++s) {
    int idx = s * 256 + tid;
    int m = idx >> 4, ch = (idx & 15) * 8;
    *(u16x8*)&Gp[(size_t)m * 768 + ch] = *(const u16x8*)&base[m * 128 + ch];
  }
}

// ---------------------------------------------------------------------------
// combine: C = sum_k e_k * (G[0]+G[1]); xWgT + spb/tpb + GLU -> hTout;
// per-t GFS partial -> ypt fp32. grid 192 = (b,t) x mt(4).
// ---------------------------------------------------------------------------
__global__ __launch_bounds__(256) void combine_kernel(
    const u16* __restrict__ G, const float* __restrict__ evl,
    const u16* __restrict__ WgTl, const float* __restrict__ spbl,
    const float* __restrict__ tpbl, const u16* __restrict__ fswTl,
    u16* __restrict__ hTout, float* __restrict__ yptl) {
  __shared__ u16 aggL[128][72];
  __shared__ u16 hL[128][72];
  const int tid = threadIdx.x, wid = tid >> 6, lane = tid & 63;
  const int l16 = lane & 15, quad = lane >> 4;
  const int bid = blockIdx.x;
  const int mt = bid & 3;
  const int bt = bid >> 2;
  const int b = bt / 12, t = bt - b * 12;

  {  // combine G halves over k (fp32), thread = (j, 32-c half)
    int j = tid >> 1;
    int c0 = (tid & 1) * 32;
    float accv[32];
    #pragma unroll
    for (int ii = 0; ii < 32; ++ii) accv[ii] = 0.f;
    #pragma unroll
    for (int k = 0; k < 3; ++k) {
      int tp = t + k - 2;
      if (tp < 0) continue;
      float ek = evl[bt * 3 + k];
      const u16* gp0 = &G[((size_t)((b * 3 + k) * 512 + mt * 128 + j)) * 768 + tp * 64 + c0];
      const u16* gp1 = gp0 + (size_t)GHALF;
      #pragma unroll
      for (int s = 0; s < 4; ++s) {
        u16x8 g0 = *(const u16x8*)&gp0[s * 8];
        u16x8 g1 = *(const u16x8*)&gp1[s * 8];
        #pragma unroll
        for (int ii = 0; ii < 8; ++ii)
          accv[s * 8 + ii] += (b2f(g0[ii]) + b2f(g1[ii])) * ek;
      }
    }
    #pragma unroll
    for (int s = 0; s < 4; ++s) {
      u16x8 ov;
      #pragma unroll
      for (int ii = 0; ii < 8; ++ii) ov[ii] = f2b(accv[s * 8 + ii]);
      *(u16x8*)&aggL[j][c0 + s * 8] = ov;
    }
  }
  __syncthreads();

  // phase 2: g[o,j] = sum_c WgT[o][c]*agg[j][c]
  f32x4 acc2[8][2] = {};
  #pragma unroll
  for (int ks = 0; ks < 2; ++ks) {
    short8 bf[2];
    #pragma unroll
    for (int nb = 0; nb < 2; ++nb)
      bf[nb] = *(const short8*)&aggL[wid * 32 + nb * 16 + l16][ks * 32 + quad * 8];
    #pragma unroll
    for (int mb = 0; mb < 8; ++mb) {
      short8 a = *(const short8*)&WgTl[(mb * 16 + l16) * 64 + ks * 32 + quad * 8];
      acc2[mb][0] = MFMA16(a, bf[0], acc2[mb][0]);
      acc2[mb][1] = MFMA16(a, bf[1], acc2[mb][1]);
    }
  }

  // epilogue: + spb + tpb, GLU, write hTout + hL
  #pragma unroll
  for (int mb = 0; mb < 4; ++mb) {
    int ob = mb * 16 + quad * 4;
    #pragma unroll
    for (int nb = 0; nb < 2; ++nb) {
      int jl = wid * 32 + nb * 16 + l16;
      int jg = mt * 128 + jl;
      f32x4 spl = *(const f32x4*)&spbl[jg * 128 + ob];
      f32x4 spr = *(const f32x4*)&spbl[jg * 128 + 64 + ob];
      f32x4 tpl = *(const f32x4*)&tpbl[bt * 128 + ob];
      f32x4 tpr = *(const f32x4*)&tpbl[bt * 128 + 64 + ob];
      #pragma unroll
      for (int r = 0; r < 4; ++r) {
        float vl = acc2[mb][nb][r] + spl[r] + tpl[r];
        float vr = acc2[mb + 4][nb][r] + spr[r] + tpr[r];
        u16 hb = f2b(vl * sigm(vr));
        hTout[((size_t)((b * 12 + t) * 64 + ob + r)) * 512 + jg] = hb;
        hL[jl][ob + r] = hb;
      }
    }
  }
  __syncthreads();

  // GFS partial: y_t[o][j] = sum_c fswT[o][t*64+c] * h[j][c] -> ypt fp32
  f32x4 accY[4][2] = {};
  #pragma unroll
  for (int ks = 0; ks < 2; ++ks) {
    short8 bfv[2];
    #pragma unroll
    for (int nb = 0; nb < 2; ++nb)
      bfv[nb] = *(const short8*)&hL[wid * 32 + nb * 16 + l16][ks * 32 + quad * 8];
    #pragma unroll
    for (int mb = 0; mb < 4; ++mb) {
      short8 a = *(const short8*)&fswTl[(mb * 16 + l16) * 768 + t * 64 + ks * 32 + quad * 8];
      accY[mb][0] = MFMA16(a, bfv[0], accY[mb][0]);
      accY[mb][1] = MFMA16(a, bfv[1], accY[mb][1]);
    }
  }
  #pragma unroll
  for (int mb = 0; mb < 4; ++mb)
    #pragma unroll
    for (int nb = 0; nb < 2; ++nb) {
      int j = mt * 128 + wid * 32 + nb * 16 + l16;
      #pragma unroll
      for (int r = 0; r < 4; ++r) {
        int o = mb * 16 + quad * 4 + r;
        yptl[((size_t)(bt * 64 + o)) * 512 + j] = accY[mb][nb][r];
      }
    }
}

// ---------------------------------------------------------------------------
// reduce (R9-identical): yB[l][b][o][v] = bf16(sum_t ypt + fsb). grid 512.
// ---------------------------------------------------------------------------
__global__ __launch_bounds__(256) void reduce_kernel(
    const float* __restrict__ ypt, const float* __restrict__ fsb,
    u16* __restrict__ yB) {
  int gid = blockIdx.x * 256 + threadIdx.x;    // 131072
  int j4 = gid & 127, o = (gid >> 7) & 63, b = (gid >> 13) & 3, l = gid >> 15;
  const float* base = &ypt[(size_t)l * 1572864 +
                           ((size_t)((b * 12) * 64 + o)) * 512 + j4 * 4];
  float fb = fsb[l * 64 + o];
  f32x4 s = {fb, fb, fb, fb};
  #pragma unroll
  for (int t = 0; t < 12; ++t) s += *(const f32x4*)&base[(size_t)t * 32768];
  u16x4 pk;
  #pragma unroll
  for (int ii = 0; ii < 4; ++ii) pk[ii] = f2b(s[ii]);
  *(u16x4*)&yB[((size_t)((l * 4 + b) * 64 + o)) * 512 + j4 * 4] = pk;
}

// ---------------------------------------------------------------------------
// glu1cat (R9-identical)
// ---------------------------------------------------------------------------
__global__ __launch_bounds__(256) void glu1cat_kernel(
    const u16* __restrict__ yB, const u16* __restrict__ g1wB,
    const float* __restrict__ g1b, u16* __restrict__ catB) {
  __shared__ u16 yL[128][72];
  const int tid = threadIdx.x, wid = tid >> 6, lane = tid & 63;
  const int l16 = lane & 15, quad = lane >> 4;
  const int l = blockIdx.x >> 4;
  const int b = (blockIdx.x >> 2) & 3;
  const int v0 = (blockIdx.x & 3) * 128;

  {
    int o = tid & 63, sv = tid >> 6;
    const u16* src = &yB[((size_t)((l * 4 + b) * 64 + o)) * 512 + v0 + sv * 32];
    u16x8 p0 = *(const u16x8*)&src[0];
    u16x8 p1 = *(const u16x8*)&src[8];
    u16x8 p2 = *(const u16x8*)&src[16];
    u16x8 p3 = *(const u16x8*)&src[24];
    #pragma unroll
    for (int ii = 0; ii < 8; ++ii) {
      yL[sv * 32 + ii][o] = p0[ii];
      yL[sv * 32 + 8 + ii][o] = p1[ii];
      yL[sv * 32 + 16 + ii][o] = p2[ii];
      yL[sv * 32 + 24 + ii][o] = p3[ii];
    }
  }
  __syncthreads();

  f32x4 acc[2][8] = {};
  #pragma unroll
  for (int ks = 0; ks < 2; ++ks) {
    short8 a0 = *(const short8*)&g1wB[l * 8192 + (wid * 16 + l16) * 64 +
                                      ks * 32 + quad * 8];
    short8 a1 = *(const short8*)&g1wB[l * 8192 + (64 + wid * 16 + l16) * 64 +
                                      ks * 32 + quad * 8];
    #pragma unroll
    for (int nb = 0; nb < 8; ++nb) {
      short8 bf = *(const short8*)&yL[nb * 16 + l16][ks * 32 + quad * 8];
      acc[0][nb] = MFMA16(a0, bf, acc[0][nb]);
      acc[1][nb] = MFMA16(a1, bf, acc[1][nb]);
    }
  }
  #pragma unroll
  for (int nb = 0; nb < 8; ++nb) {
    int v = v0 + nb * 16 + l16;
    int oc = wid * 16 + quad * 4;
    u16x4 pk;
    #pragma unroll
    for (int r = 0; r < 4; ++r) {
      float zl = acc[0][nb][r] + g1b[l * 128 + oc + r];
      float zr = acc[1][nb][r] + g1b[l * 128 + 64 + oc + r];
      pk[r] = f2b(zl * sigm(zr));
    }
    *(u16x4*)&catB[((size_t)(b * 512 + v)) * 256 + l * 64 + oc] = pk;
  }
}

// ---------------------------------------------------------------------------
// gout (R9-identical)
// ---------------------------------------------------------------------------
__global__ __launch_bounds__(256) void gout_kernel(
    const u16* __restrict__ catB, const u16* __restrict__ gwB,
    const float* __restrict__ gb, u16* __restrict__ sB) {
  __shared__ u16 cL[64][264];
  const int tid = threadIdx.x, wid = tid >> 6, lane = tid & 63;
  const int l16 = lane & 15, quad = lane >> 4;
  const int wm = wid >> 1, wn = wid & 1;
  const int b = blockIdx.x >> 6;
  const int v0 = ((blockIdx.x >> 3) & 7) * 64;
  const int cc0 = (blockIdx.x & 7) * 32;

  {
    int v = tid >> 2, seg = (tid & 3) * 64;
    const u16* src = &catB[((size_t)(b * 512 + v0 + v)) * 256 + seg];
    #pragma unroll
    for (int s = 0; s < 8; ++s)
      *(u16x8*)&cL[v][seg + s * 8] = *(const u16x8*)&src[s * 8];
  }
  __syncthreads();

  f32x4 acc[2][2] = {};
  #pragma unroll
  for (int ks = 0; ks < 8; ++ks) {
    short8 aL = *(const short8*)&gwB[(cc0 + wm * 16 + l16) * 256 +
                                     ks * 32 + quad * 8];
    short8 aH = *(const short8*)&gwB[(256 + cc0 + wm * 16 + l16) * 256 +
                                     ks * 32 + quad * 8];
    #pragma unroll
    for (int nb = 0; nb < 2; ++nb) {
      short8 bf = *(const short8*)&cL[wn * 32 + nb * 16 + l16][ks * 32 + quad * 8];
      acc[0][nb] = MFMA16(aL, bf, acc[0][nb]);
      acc[1][nb] = MFMA16(aH, bf, acc[1][nb]);
    }
  }
  #pragma unroll
  for (int nb = 0; nb < 2; ++nb) {
    int v = v0 + wn * 32 + nb * 16 + l16;
    int cc = cc0 + wm * 16 + quad * 4;
    u16x4 pk;
    #pragma unroll
    for (int r = 0; r < 4; ++r) {
      float zl = acc[0][nb][r] + gb[cc + r];
      float zr = acc[1][nb][r] + gb[256 + cc + r];
      pk[r] = f2b(zl * sigm(zr));
    }
    *(u16x4*)&sB[((size_t)(b * 512 + v)) * 256 + cc] = pk;
  }
}

// ---------------------------------------------------------------------------
// head (R9-identical)
// ---------------------------------------------------------------------------
__global__ __launch_bounds__(256) void head_kernel(
    const u16* __restrict__ sB, const u16* __restrict__ owB,
    const float* __restrict__ obv, float* __restrict__ out) {
  const int tid = threadIdx.x, wid = tid >> 6, lane = tid & 63;
  const int l16 = lane & 15, quad = lane >> 4;
  const int b = blockIdx.x >> 3;
  const int v0 = (blockIdx.x & 7) * 64;

  f32x4 acc = {};
  #pragma unroll
  for (int ks = 0; ks < 8; ++ks) {
    short8 a;
    if (l16 < 12) a = *(const short8*)&owB[l16 * 256 + ks * 32 + quad * 8];
    else {
      #pragma unroll
      for (int ii = 0; ii < 8; ++ii) a[ii] = 0;
    }
    short8 bf = *(const short8*)&sB[((size_t)(b * 512 + v0 + wid * 16 + l16)) * 256 +
                                    ks * 32 + quad * 8];
    acc = MFMA16(a, bf, acc);
  }
  #pragma unroll
  for (int r = 0; r < 4; ++r) {
    int p = quad * 4 + r;
    if (p < 12)
      out[(b * 12 + p) * 512 + v0 + wid * 16 + l16] = acc[r] + obv[p];
  }
}

// ---------------------------------------------------------------------------
extern "C" void kernel_launch(void* const* d_in, const int* in_sizes, int n_in,
                              void* d_out, int out_size, void* d_ws, size_t ws_size,
                              hipStream_t stream) {
  const float* x    = (const float*)d_in[0];
  const float* sape = (const float*)d_in[1];
  const float* tape = (const float*)d_in[2];
  const float* srpe = (const float*)d_in[3];
  const float* trpe = (const float*)d_in[4];
  const float* mask = (const float*)d_in[7];
  const float* Wi   = (const float*)d_in[8];
  const float* bi   = (const float*)d_in[9];
  const float* gmu  = (const float*)d_in[10];
  const float* gsg  = (const float*)d_in[11];
  const float* Wg   = (const float*)d_in[12];
  const float* bg   = (const float*)d_in[13];
  const float* Wsp  = (const float*)d_in[14];
  const float* Wtp  = (const float*)d_in[15];
  const float* fsw  = (const float*)d_in[16];
  const float* fsb  = (const float*)d_in[17];
  const float* g1w  = (const float*)d_in[18];
  const float* g1b  = (const float*)d_in[19];
  const float* gow  = (const float*)d_in[20];
  const float* gob  = (const float*)d_in[21];
  const float* ow   = (const float*)d_in[22];
  const float* obv  = (const float*)d_in[23];

  char* w = (char*)d_ws;
  u16*   hT_a  = (u16*)(w + 0);           // 3,145,728 B
  u16*   hT_b  = (u16*)(w + 3145728);     // 3,145,728 B
  u16*   expbT = (u16*)(w + 6291456);     // 2,097,152 B (4 layers)
  u64*   mbits = (u64*)(w + 8388608);     // 393,216 B
  u16*   G     = (u16*)(w + 8781824);     // 37,748,736 B (2 halves x 18,874,368)
  u16*   fswT  = (u16*)(w + 46530560);    // 393,216 B
  u16*   WgT   = (u16*)(w + 46923776);    // 65,536 B
  u16*   g1wB  = (u16*)(w + 46989312);    // 65,536 B
  u16*   gwB   = (u16*)(w + 47054848);    // 262,144 B
  u16*   owB   = (u16*)(w + 47316992);    // 8,192 B
  float* spb   = (float*)(w + 47325184);  // 1,048,576 B
  float* tpb   = (float*)(w + 48373760);  // 98,304 B
  float* ev    = (float*)(w + 48472064);  // 16,384 B
  float* ypt   = (float*)(w + 48488448);  // 25,165,824 B
  u16*   yB    = (u16*)(w + 73654272);    // 2,097,152 B
  u16*   catB  = (u16*)(w + 75751424);    // 1,048,576 B
  u16*   sB    = (u16*)(w + 76800000);    // 1,048,576 B

  prep_kernel<<<4463, 256, 0, stream>>>(x, sape, tape, srpe, trpe, Wi, bi, gmu, gsg,
                                        Wg, bg, Wsp, Wtp, fsw, mask, g1w, gow, ow,
                                        hT_a, expbT, mbits, spb, tpb, fswT, WgT, ev,
                                        g1wB, gwB, owB);
  u16* hin = hT_a;
  u16* hout = hT_b;
  for (int l = 0; l < 4; ++l) {
    agg_kernel<<<576, 256, 0, stream>>>(expbT + l * 262144, (const u8*)mbits,
                                        hin, G);
    combine_kernel<<<192, 256, 0, stream>>>(G, ev + l * 144, WgT + l * 8192,
                                            spb + l * 65536, tpb + l * 6144,
                                            fswT + l * 49152, hout,
                                            ypt + (size_t)l * 1572864);
    u16* tmp = hin; hin = hout; hout = tmp;
  }
  reduce_kernel<<<512, 256, 0, stream>>>(ypt, fsb, yB);
  glu1cat_kernel<<<64, 256, 0, stream>>>(yB, g1wB, g1b, catB);
  gout_kernel<<<256, 256, 0, stream>>>(catB, gwB, gob, sB);
  head_kernel<<<32, 256, 0, stream>>>(sB, owB, obv, (float*)d_out);
}